// Round 1
// baseline (5378.632 us; speedup 1.0000x reference)
//
#include <hip/hip_runtime.h>

// ---------------- problem constants ----------------
#define BB 32
#define TT 64
#define PP 10
#define HH 1024
#define CC 8
#define MM 20480      // BB*TT*PP rows of x_flat
#define NN 5120       // 5*HH  ([Wx;Wih] rows, and [Wh;Whh] rows)
#define KK 1024       // I == H
#define NBLK 160      // persistent recurrence grid (<=256 CUs -> co-resident)

typedef __attribute__((ext_vector_type(4))) float    f32x4;
typedef __attribute__((ext_vector_type(4))) _Float16 f16x4;
typedef __attribute__((ext_vector_type(8))) _Float16 f16x8;

#define AS1C(p) ((const __attribute__((address_space(1))) void*)(p))
#define AS3(p)  ((__attribute__((address_space(3))) void*)(p))

__device__ __forceinline__ float fast_tanh(float x) {
  float ax = __builtin_fabsf(x);
  float e  = __expf(2.0f * ax);
  float r  = 1.0f - 2.0f / (e + 1.0f);   // -> 1 as e -> inf (no NaN)
  return __builtin_copysignf(r, x);
}
__device__ __forceinline__ float fast_sigm(float x) {
  return 1.0f / (1.0f + __expf(-x));
}

// ---------------- fp32 -> fp16 conversion / weight concat ----------------
__global__ void convert_kernel(const float* __restrict__ x,
                               const float* __restrict__ Wx,
                               const float* __restrict__ Wih,
                               const float* __restrict__ Wh,
                               const float* __restrict__ Whh,
                               _Float16* __restrict__ xh,
                               _Float16* __restrict__ w5,
                               _Float16* __restrict__ w2)
{
  const long gid    = (long)blockIdx.x * blockDim.x + threadIdx.x;
  const long stride = (long)gridDim.x * blockDim.x;
  auto cvt = [&](const float* src, _Float16* dst, long n4) {
    const f32x4* s4 = (const f32x4*)src;
    f16x4* d4 = (f16x4*)dst;
    for (long i = gid; i < n4; i += stride)
      d4[i] = __builtin_convertvector(s4[i], f16x4);
  };
  cvt(x,   xh,                 (long)MM * KK / 4);
  cvt(Wx,  w5,                 (long)HH * KK / 4);
  cvt(Wih, w5 + (long)HH * KK, (long)4 * HH * KK / 4);
  cvt(Wh,  w2,                 (long)HH * KK / 4);
  cvt(Whh, w2 + (long)HH * KK, (long)4 * HH * KK / 4);
}

// ---------------- big precompute GEMM: xW5 = x_f16 @ [Wx;Wih]^T ----------------
// A: (MM,KK) row-major fp16 ; B: (NN,KK) row-major fp16 ; C: (MM,NN) fp16.
// m97-style: 128x128 tile, 256 thr (4 waves, 2x2), BK=64, global_load_lds(16B).
__global__ __launch_bounds__(256) void gemm_kernel(const _Float16* __restrict__ A,
                                                   const _Float16* __restrict__ Bw,
                                                   _Float16* __restrict__ Cw)
{
  __shared__ __align__(16) _Float16 sA[128 * 64];
  __shared__ __align__(16) _Float16 sB[128 * 64];
  const int t    = threadIdx.x;
  const int lane = t & 63;
  const int wave = t >> 6;
  const int wm = wave >> 1, wn = wave & 1;
  const int q = lane >> 4, cl = lane & 15;

  // panel swizzle: 10 panels of 16 m-tiles x 40 n-tiles for L2/L3 reuse
  const int gid   = blockIdx.x;
  const int panel = gid / 640;
  const int w     = gid % 640;
  const int bm = panel * 16 + (w & 15);  // 0..159
  const int bn = w >> 4;                 // 0..39

  const _Float16* Ag = A  + (size_t)bm * 128 * KK;
  const _Float16* Bg = Bw + (size_t)bn * 128 * KK;

  f32x4 acc[4][4];
#pragma unroll
  for (int mi = 0; mi < 4; mi++)
#pragma unroll
    for (int ni = 0; ni < 4; ni++)
      acc[mi][ni] = (f32x4){0.f, 0.f, 0.f, 0.f};

  for (int k0 = 0; k0 < KK; k0 += 64) {
#pragma unroll
    for (int i = 0; i < 4; i++) {
      int c = t + 256 * i;          // 16B chunk id, 1024 chunks per tile
      int row = c >> 3, col8 = c & 7;
      __builtin_amdgcn_global_load_lds(AS1C(Ag + (size_t)row * KK + k0 + col8 * 8),
                                       AS3(sA + c * 8), 16, 0, 0);
      __builtin_amdgcn_global_load_lds(AS1C(Bg + (size_t)row * KK + k0 + col8 * 8),
                                       AS3(sB + c * 8), 16, 0, 0);
    }
    __syncthreads();
#pragma unroll
    for (int ks = 0; ks < 2; ks++) {
      f16x8 af[4], bf[4];
#pragma unroll
      for (int mi = 0; mi < 4; mi++)
        af[mi] = *(const f16x8*)(sA + (wm * 64 + mi * 16 + cl) * 64 + ks * 32 + q * 8);
#pragma unroll
      for (int ni = 0; ni < 4; ni++)
        bf[ni] = *(const f16x8*)(sB + (wn * 64 + ni * 16 + cl) * 64 + ks * 32 + q * 8);
#pragma unroll
      for (int mi = 0; mi < 4; mi++)
#pragma unroll
        for (int ni = 0; ni < 4; ni++)
          acc[mi][ni] = __builtin_amdgcn_mfma_f32_16x16x32_f16(af[mi], bf[ni], acc[mi][ni], 0, 0, 0);
    }
    __syncthreads();
  }

#pragma unroll
  for (int mi = 0; mi < 4; mi++)
#pragma unroll
    for (int ni = 0; ni < 4; ni++)
#pragma unroll
      for (int r = 0; r < 4; r++) {
        int row = bm * 128 + wm * 64 + mi * 16 + q * 4 + r;
        int col = bn * 128 + wn * 64 + ni * 16 + cl;
        Cw[(size_t)row * NN + col] = (_Float16)acc[mi][ni][r];
      }
}

// ---------------- device-wide barrier (persistent kernel) ----------------
__device__ __forceinline__ void grid_barrier(int* bar) {
  __syncthreads();
  if (threadIdx.x == 0) {
    __threadfence();   // release: push this block's stores device-wide
    int* cnt = bar;
    int* gen = bar + 1;
    int g = __hip_atomic_load(gen, __ATOMIC_RELAXED, __HIP_MEMORY_SCOPE_AGENT);
    int a = __hip_atomic_fetch_add(cnt, 1, __ATOMIC_ACQ_REL, __HIP_MEMORY_SCOPE_AGENT);
    if (a == NBLK - 1) {
      __hip_atomic_store(cnt, 0, __ATOMIC_RELAXED, __HIP_MEMORY_SCOPE_AGENT);
      __hip_atomic_store(gen, g + 1, __ATOMIC_RELEASE, __HIP_MEMORY_SCOPE_AGENT);
    } else {
      while (__hip_atomic_load(gen, __ATOMIC_ACQUIRE, __HIP_MEMORY_SCOPE_AGENT) == g)
        __builtin_amdgcn_s_sleep(1);
    }
    __threadfence();   // acquire: invalidate stale caches
  }
  __syncthreads();
}

// ---------------- persistent recurrence kernel ----------------
// per step: R1: a5 = h16 @ [Wh;Whh]^T (fp16 MFMA; 640 wave-jobs = 320 n-tiles x 2 k-halves)
//           barrier
//           R23: (128 blocks = 32 b x 4 unit-slices) scores(tanh)+softmax (redundant per b),
//                gates = a5 + bias + sum_p alpha_p * xW5[gate cols], LSTM pointwise
//           barrier
__global__ __launch_bounds__(256) void recur_kernel(
    const _Float16* __restrict__ xw,   // [MM][NN] fp16: cols 0..1023 att, 1024.. gates
    const _Float16* __restrict__ w2,   // [NN][KK] fp16: [Wh;Whh]
    float* __restrict__ a5a,           // [BB][NN] partial (k-half 0)
    float* __restrict__ a5b,           // [BB][NN] partial (k-half 1)
    float* __restrict__ h,             // [BB][HH] fp32
    float* __restrict__ c,             // [BB][HH] fp32
    _Float16* __restrict__ h16,        // [BB][HH] fp16 (MFMA A operand)
    int* __restrict__ bar,
    const float* __restrict__ b_att,
    const float* __restrict__ v,
    const float* __restrict__ bih,
    const float* __restrict__ bhh,
    const float* __restrict__ Wfc,
    const float* __restrict__ bfc,
    float* __restrict__ out)
{
  const int tid  = threadIdx.x;
  const int bid  = blockIdx.x;
  const int lane = tid & 63;
  const int wave = tid >> 6;
  const int q = lane >> 4, cl = lane & 15;

  __shared__ float red[4][PP];
  __shared__ float alpha_s[PP];

  // zero-init recurrent state (h16, c); ws is poisoned 0xAA each launch
  if (bid < BB) {
    ((f32x4*)c)[bid * 256 + tid]   = (f32x4){0.f, 0.f, 0.f, 0.f};
    ((f16x4*)h16)[bid * 256 + tid] = (f16x4){(_Float16)0.f, (_Float16)0.f, (_Float16)0.f, (_Float16)0.f};
  }
  grid_barrier(bar);

  const int job = bid * 4 + wave;          // 0..639
  const int nt  = job >> 1;                // n-tile 0..319
  const int kh  = job & 1;                 // k-half
  const _Float16* Ab = h16 + (size_t)cl * KK + kh * 512 + q * 8;                 // A[m=cl][k]
  const _Float16* Bb = w2 + ((size_t)(nt * 16 + cl)) * KK + kh * 512 + q * 8;    // B[n=cl][k]
  float* a5w = kh ? a5b : a5a;

  for (int t = 0; t < TT; ++t) {
    // ---------- R1 ----------
    {
      f32x4 acc0 = {0.f, 0.f, 0.f, 0.f}, acc1 = {0.f, 0.f, 0.f, 0.f};
#pragma unroll 4
      for (int ks = 0; ks < 16; ks++) {
        f16x8 bfr = *(const f16x8*)(Bb + ks * 32);
        f16x8 a0  = *(const f16x8*)(Ab + ks * 32);
        f16x8 a1  = *(const f16x8*)(Ab + (size_t)16 * KK + ks * 32);
        acc0 = __builtin_amdgcn_mfma_f32_16x16x32_f16(a0, bfr, acc0, 0, 0, 0);
        acc1 = __builtin_amdgcn_mfma_f32_16x16x32_f16(a1, bfr, acc1, 0, 0, 0);
      }
#pragma unroll
      for (int r = 0; r < 4; r++) {
        a5w[(size_t)(q * 4 + r) * NN + nt * 16 + cl]        = acc0[r];  // b rows 0..15
        a5w[(size_t)(16 + q * 4 + r) * NN + nt * 16 + cl]   = acc1[r];  // b rows 16..31
      }
    }
    grid_barrier(bar);

    // ---------- R23 ----------
    if (bid < 128) {
      const int b  = bid & 31;
      const int us = bid >> 5;
      const size_t rbase = ((size_t)b * TT + t) * PP;   // row of x_flat for (b,t,p=0)

      // scores: s[p] = sum_h v[h] * tanh(xW[h] + a5[h] + b_att[h])   (thread: 4 h)
      f32x4 vv = ((const f32x4*)v)[tid];
      f32x4 aa = ((const f32x4*)(a5a + (size_t)b * NN))[tid]
               + ((const f32x4*)(a5b + (size_t)b * NN))[tid]
               + ((const f32x4*)b_att)[tid];
      float part[PP];
#pragma unroll
      for (int p = 0; p < PP; p++) {
        f16x4 xv = ((const f16x4*)(xw + (rbase + p) * NN))[tid];
        f32x4 xf = __builtin_convertvector(xv, f32x4);
        float s = 0.f;
#pragma unroll
        for (int j = 0; j < 4; j++)
          s += vv[j] * fast_tanh(aa[j] + xf[j]);
        part[p] = s;
      }
#pragma unroll
      for (int p = 0; p < PP; p++) {
        float s = part[p];
        s += __shfl_down(s, 32); s += __shfl_down(s, 16); s += __shfl_down(s, 8);
        s += __shfl_down(s, 4);  s += __shfl_down(s, 2);  s += __shfl_down(s, 1);
        if (lane == 0) red[wave][p] = s;
      }
      __syncthreads();
      if (tid == 0) {
        float sc[PP]; float mx = -1e30f;
#pragma unroll
        for (int p = 0; p < PP; p++) {
          sc[p] = red[0][p] + red[1][p] + red[2][p] + red[3][p];
          mx = fmaxf(mx, sc[p]);
        }
        float den = 0.f;
#pragma unroll
        for (int p = 0; p < PP; p++) { sc[p] = __expf(sc[p] - mx); den += sc[p]; }
        float inv = 1.0f / den;
#pragma unroll
        for (int p = 0; p < PP; p++) alpha_s[p] = sc[p] * inv;
      }
      __syncthreads();
      float al[PP];
#pragma unroll
      for (int p = 0; p < PP; p++) al[p] = alpha_s[p];

      // gates + LSTM pointwise for unit u
      const int u = us * 256 + tid;
      float gv[4];
#pragma unroll
      for (int gi = 0; gi < 4; gi++) {
        int n = HH + gi * HH + u;
        float s = a5a[(size_t)b * NN + n] + a5b[(size_t)b * NN + n]
                + bih[gi * HH + u] + bhh[gi * HH + u];
#pragma unroll
        for (int p = 0; p < PP; p++)
          s += al[p] * (float)xw[(rbase + p) * NN + n];
        gv[gi] = s;
      }
      float cold = c[(size_t)b * HH + u];
      float ig = fast_sigm(gv[0]);
      float fg = fast_sigm(gv[1]);
      float gg = fast_tanh(gv[2]);
      float og = fast_sigm(gv[3]);
      float cn = fg * cold + ig * gg;
      float hn = og * fast_tanh(cn);
      c[(size_t)b * HH + u]   = cn;
      h[(size_t)b * HH + u]   = hn;
      h16[(size_t)b * HH + u] = (_Float16)hn;
    }
    grid_barrier(bar);
  }

  // ---------- final FC: out = h @ Wfc^T + bfc ----------
  if (bid < BB) {
    const int b = bid;
    f32x4 hv = ((const f32x4*)(h + (size_t)b * HH))[tid];
    float pc[CC];
#pragma unroll
    for (int cc2 = 0; cc2 < CC; cc2++) {
      f32x4 wv = ((const f32x4*)(Wfc + (size_t)cc2 * HH))[tid];
      pc[cc2] = hv[0]*wv[0] + hv[1]*wv[1] + hv[2]*wv[2] + hv[3]*wv[3];
    }
#pragma unroll
    for (int cc2 = 0; cc2 < CC; cc2++) {
      float s = pc[cc2];
      s += __shfl_down(s, 32); s += __shfl_down(s, 16); s += __shfl_down(s, 8);
      s += __shfl_down(s, 4);  s += __shfl_down(s, 2);  s += __shfl_down(s, 1);
      if (lane == 0) red[wave][cc2] = s;
    }
    __syncthreads();
    if (tid < CC)
      out[b * CC + tid] = red[0][tid] + red[1][tid] + red[2][tid] + red[3][tid] + bfc[tid];
  }
}

// ---------------- host entry ----------------
extern "C" void kernel_launch(void* const* d_in, const int* in_sizes, int n_in,
                              void* d_out, int out_size, void* d_ws, size_t ws_size,
                              hipStream_t stream)
{
  (void)in_sizes; (void)n_in; (void)out_size; (void)ws_size;
  const float* x     = (const float*)d_in[0];
  const float* Wx    = (const float*)d_in[1];
  const float* Wh    = (const float*)d_in[2];
  const float* b_att = (const float*)d_in[3];
  const float* v     = (const float*)d_in[4];
  const float* Wih   = (const float*)d_in[5];
  const float* Whh   = (const float*)d_in[6];
  const float* bih   = (const float*)d_in[7];
  const float* bhh   = (const float*)d_in[8];
  const float* Wfc   = (const float*)d_in[9];
  const float* bfc   = (const float*)d_in[10];
  float* out = (float*)d_out;

  char* ws = (char*)d_ws;
  size_t off = 0;
  auto alloc = [&](size_t bytes) {
    size_t o = off;
    off += (bytes + 255) & ~(size_t)255;
    return o;
  };
  int*      bar = (int*)      (ws + alloc(256));
  _Float16* xh  = (_Float16*) (ws + alloc((size_t)MM * KK * 2));   //  42 MB
  _Float16* w5  = (_Float16*) (ws + alloc((size_t)NN * KK * 2));   //  10.5 MB
  _Float16* w2  = (_Float16*) (ws + alloc((size_t)NN * KK * 2));   //  10.5 MB
  _Float16* xw  = (_Float16*) (ws + alloc((size_t)MM * NN * 2));   // 210 MB
  float*    a5a = (float*)    (ws + alloc((size_t)BB * NN * 4));
  float*    a5b = (float*)    (ws + alloc((size_t)BB * NN * 4));
  float*    h   = (float*)    (ws + alloc((size_t)BB * HH * 4));
  float*    c   = (float*)    (ws + alloc((size_t)BB * HH * 4));
  _Float16* h16 = (_Float16*) (ws + alloc((size_t)BB * HH * 2));

  hipMemsetAsync(bar, 0, 8, stream);   // barrier cnt/gen (ws is poisoned each launch)
  convert_kernel<<<2048, 256, 0, stream>>>(x, Wx, Wih, Wh, Whh, xh, w5, w2);
  gemm_kernel<<<6400, 256, 0, stream>>>(xh, w5, xw);
  recur_kernel<<<NBLK, 256, 0, stream>>>(xw, w2, a5a, a5b, h, c, h16, bar,
                                         b_att, v, bih, bhh, Wfc, bfc, out);
}

// Round 2
// 1397.265 us; speedup vs baseline: 3.8494x; 3.8494x over previous
//
#include <hip/hip_runtime.h>

// ---------------- problem constants ----------------
#define BB 32
#define TT 64
#define PP 10
#define HH 1024
#define CC 8
#define MM 20480      // BB*TT*PP rows of x_flat
#define NN 5120       // 5*HH  ([Wx;Wih] rows, and [Wh;Whh] rows)
#define KK 1024       // I == H
#define NBLK 160      // persistent recurrence grid (<=256 CUs -> co-resident)
#define GEN_OFF (NBLK * 16)

typedef __attribute__((ext_vector_type(4))) float    f32x4;
typedef __attribute__((ext_vector_type(4))) _Float16 f16x4;
typedef __attribute__((ext_vector_type(8))) _Float16 f16x8;

#define AS1C(p) ((const __attribute__((address_space(1))) void*)(p))
#define AS3(p)  ((__attribute__((address_space(3))) void*)(p))

__device__ __forceinline__ float fast_tanh(float x) {
  float ax = __builtin_fabsf(x);
  float e  = __expf(2.0f * ax);
  float r  = 1.0f - 2.0f / (e + 1.0f);   // -> 1 as e -> inf (no NaN)
  return __builtin_copysignf(r, x);
}
__device__ __forceinline__ float fast_sigm(float x) {
  return 1.0f / (1.0f + __expf(-x));
}

// ---------- coherence-point (sc0 sc1) access helpers: bypass L1+L2 ----------
__device__ __forceinline__ int ld_flag(const int* p) {
  int r;
  asm volatile("global_load_dword %0, %1, off sc0 sc1\n\ts_waitcnt vmcnt(0)"
               : "=v"(r) : "v"(p) : "memory");
  return r;
}
__device__ __forceinline__ void st_flag(int* p, int v) {
  asm volatile("global_store_dword %0, %1, off sc0 sc1\n\ts_waitcnt vmcnt(0)"
               :: "v"(p), "v"(v) : "memory");
}
__device__ __forceinline__ void st_f32_sc(float* p, float v) {
  asm volatile("global_store_dword %0, %1, off sc0 sc1" :: "v"(p), "v"(v) : "memory");
}
__device__ __forceinline__ void st_u32_sc(unsigned* p, unsigned v) {
  asm volatile("global_store_dword %0, %1, off sc0 sc1" :: "v"(p), "v"(v) : "memory");
}
__device__ __forceinline__ void st_u16_sc(unsigned short* p, unsigned v) {
  asm volatile("global_store_short %0, %1, off sc0 sc1" :: "v"(p), "v"(v) : "memory");
}
__device__ __forceinline__ f32x4 ld_f32x4_sc(const float* p) {
  f32x4 r;
  asm volatile("global_load_dwordx4 %0, %1, off sc0 sc1\n\ts_waitcnt vmcnt(0)"
               : "=v"(r) : "v"(p) : "memory");
  return r;
}
// 8 x 16B A-fragment loads, single latency window
__device__ __forceinline__ void load_a8_sc(
    const _Float16* p0, const _Float16* p1, const _Float16* p2, const _Float16* p3,
    const _Float16* p4, const _Float16* p5, const _Float16* p6, const _Float16* p7,
    f16x8& d0, f16x8& d1, f16x8& d2, f16x8& d3,
    f16x8& d4, f16x8& d5, f16x8& d6, f16x8& d7)
{
  asm volatile(
    "global_load_dwordx4 %0, %8, off sc0 sc1\n\t"
    "global_load_dwordx4 %1, %9, off sc0 sc1\n\t"
    "global_load_dwordx4 %2, %10, off sc0 sc1\n\t"
    "global_load_dwordx4 %3, %11, off sc0 sc1\n\t"
    "global_load_dwordx4 %4, %12, off sc0 sc1\n\t"
    "global_load_dwordx4 %5, %13, off sc0 sc1\n\t"
    "global_load_dwordx4 %6, %14, off sc0 sc1\n\t"
    "global_load_dwordx4 %7, %15, off sc0 sc1\n\t"
    "s_waitcnt vmcnt(0)"
    : "=v"(d0), "=v"(d1), "=v"(d2), "=v"(d3), "=v"(d4), "=v"(d5), "=v"(d6), "=v"(d7)
    : "v"(p0), "v"(p1), "v"(p2), "v"(p3), "v"(p4), "v"(p5), "v"(p6), "v"(p7)
    : "memory");
}
// att (2 x dwordx4) + gates (8 x dword) in one latency window
__device__ __forceinline__ void ld_att_gates_sc(
    const float* pa, const float* pb,
    const float* q0, const float* q1, const float* q2, const float* q3,
    const float* q4, const float* q5, const float* q6, const float* q7,
    f32x4& ra, f32x4& rb,
    float& r0, float& r1, float& r2, float& r3,
    float& r4, float& r5, float& r6, float& r7)
{
  asm volatile(
    "global_load_dwordx4 %0, %10, off sc0 sc1\n\t"
    "global_load_dwordx4 %1, %11, off sc0 sc1\n\t"
    "global_load_dword %2, %12, off sc0 sc1\n\t"
    "global_load_dword %3, %13, off sc0 sc1\n\t"
    "global_load_dword %4, %14, off sc0 sc1\n\t"
    "global_load_dword %5, %15, off sc0 sc1\n\t"
    "global_load_dword %6, %16, off sc0 sc1\n\t"
    "global_load_dword %7, %17, off sc0 sc1\n\t"
    "global_load_dword %8, %18, off sc0 sc1\n\t"
    "global_load_dword %9, %19, off sc0 sc1\n\t"
    "s_waitcnt vmcnt(0)"
    : "=v"(ra), "=v"(rb), "=v"(r0), "=v"(r1), "=v"(r2), "=v"(r3),
      "=v"(r4), "=v"(r5), "=v"(r6), "=v"(r7)
    : "v"(pa), "v"(pb), "v"(q0), "v"(q1), "v"(q2), "v"(q3),
      "v"(q4), "v"(q5), "v"(q6), "v"(q7)
    : "memory");
}

// ---------------- fp32 -> fp16 conversion / weight concat ----------------
__global__ void convert_kernel(const float* __restrict__ x,
                               const float* __restrict__ Wx,
                               const float* __restrict__ Wih,
                               const float* __restrict__ Wh,
                               const float* __restrict__ Whh,
                               _Float16* __restrict__ xh,
                               _Float16* __restrict__ w5,
                               _Float16* __restrict__ w2)
{
  const long gid    = (long)blockIdx.x * blockDim.x + threadIdx.x;
  const long stride = (long)gridDim.x * blockDim.x;
  auto cvt = [&](const float* src, _Float16* dst, long n4) {
    const f32x4* s4 = (const f32x4*)src;
    f16x4* d4 = (f16x4*)dst;
    for (long i = gid; i < n4; i += stride)
      d4[i] = __builtin_convertvector(s4[i], f16x4);
  };
  cvt(x,   xh,                 (long)MM * KK / 4);
  cvt(Wx,  w5,                 (long)HH * KK / 4);
  cvt(Wih, w5 + (long)HH * KK, (long)4 * HH * KK / 4);
  cvt(Wh,  w2,                 (long)HH * KK / 4);
  cvt(Whh, w2 + (long)HH * KK, (long)4 * HH * KK / 4);
}

// ---------------- big precompute GEMM: xW5 = x_f16 @ [Wx;Wih]^T ----------------
__global__ __launch_bounds__(256) void gemm_kernel(const _Float16* __restrict__ A,
                                                   const _Float16* __restrict__ Bw,
                                                   _Float16* __restrict__ Cw)
{
  __shared__ __align__(16) _Float16 sA[128 * 64];
  __shared__ __align__(16) _Float16 sB[128 * 64];
  const int t    = threadIdx.x;
  const int lane = t & 63;
  const int wave = t >> 6;
  const int wm = wave >> 1, wn = wave & 1;
  const int q = lane >> 4, cl = lane & 15;

  const int gid   = blockIdx.x;
  const int panel = gid / 640;
  const int w     = gid % 640;
  const int bm = panel * 16 + (w & 15);  // 0..159
  const int bn = w >> 4;                 // 0..39

  const _Float16* Ag = A  + (size_t)bm * 128 * KK;
  const _Float16* Bg = Bw + (size_t)bn * 128 * KK;

  f32x4 acc[4][4];
#pragma unroll
  for (int mi = 0; mi < 4; mi++)
#pragma unroll
    for (int ni = 0; ni < 4; ni++)
      acc[mi][ni] = (f32x4){0.f, 0.f, 0.f, 0.f};

  for (int k0 = 0; k0 < KK; k0 += 64) {
#pragma unroll
    for (int i = 0; i < 4; i++) {
      int c = t + 256 * i;
      int row = c >> 3, col8 = c & 7;
      __builtin_amdgcn_global_load_lds(AS1C(Ag + (size_t)row * KK + k0 + col8 * 8),
                                       AS3(sA + c * 8), 16, 0, 0);
      __builtin_amdgcn_global_load_lds(AS1C(Bg + (size_t)row * KK + k0 + col8 * 8),
                                       AS3(sB + c * 8), 16, 0, 0);
    }
    __syncthreads();
#pragma unroll
    for (int ks = 0; ks < 2; ks++) {
      f16x8 af[4], bf[4];
#pragma unroll
      for (int mi = 0; mi < 4; mi++)
        af[mi] = *(const f16x8*)(sA + (wm * 64 + mi * 16 + cl) * 64 + ks * 32 + q * 8);
#pragma unroll
      for (int ni = 0; ni < 4; ni++)
        bf[ni] = *(const f16x8*)(sB + (wn * 64 + ni * 16 + cl) * 64 + ks * 32 + q * 8);
#pragma unroll
      for (int mi = 0; mi < 4; mi++)
#pragma unroll
        for (int ni = 0; ni < 4; ni++)
          acc[mi][ni] = __builtin_amdgcn_mfma_f32_16x16x32_f16(af[mi], bf[ni], acc[mi][ni], 0, 0, 0);
    }
    __syncthreads();
  }

#pragma unroll
  for (int mi = 0; mi < 4; mi++)
#pragma unroll
    for (int ni = 0; ni < 4; ni++)
#pragma unroll
      for (int r = 0; r < 4; r++) {
        int row = bm * 128 + wm * 64 + mi * 16 + q * 4 + r;
        int col = bn * 128 + wn * 64 + ni * 16 + cl;
        Cw[(size_t)row * NN + col] = (_Float16)acc[mi][ni][r];
      }
}

// ---------------- flag-tree device barrier (no cache maintenance) ----------------
// All shared data moves via sc0/sc1 ops, so L2 never holds dirty shared lines and
// no buffer_wbl2/inv is needed. Producer ordering: vmcnt(0) before flag store.
__device__ __forceinline__ void grid_barrier(int* flags, int ph) {
  asm volatile("s_waitcnt vmcnt(0)" ::: "memory");  // all sc-stores at LLC
  __syncthreads();
  if (blockIdx.x == 0) {
    const int tid = threadIdx.x;
    if (tid >= 1 && tid < NBLK)
      while (ld_flag(flags + tid * 16) < ph) {}
    __syncthreads();
    if (tid == 0) st_flag(flags + GEN_OFF, ph);
  } else {
    if (threadIdx.x == 0) {
      st_flag(flags + blockIdx.x * 16, ph);
      while (ld_flag(flags + GEN_OFF) < ph) {}
    }
  }
  __syncthreads();
}

// ---------------- persistent recurrence kernel ----------------
__global__ __launch_bounds__(256) void recur_kernel(
    const _Float16* __restrict__ xw,   // [MM][NN] fp16: cols 0..1023 att, 1024.. gates
    const _Float16* __restrict__ w2,   // [NN][KK] fp16: [Wh;Whh]
    float* __restrict__ a5a,           // [BB][NN] partial (k-half 0)
    float* __restrict__ a5b,           // [BB][NN] partial (k-half 1)
    float* __restrict__ h,             // [BB][HH] fp32 (final step only)
    _Float16* __restrict__ h16,        // [BB][HH] fp16 (MFMA A operand)
    int* __restrict__ flags,
    const float* __restrict__ b_att,
    const float* __restrict__ v,
    const float* __restrict__ bih,
    const float* __restrict__ bhh,
    const float* __restrict__ Wfc,
    const float* __restrict__ bfc,
    float* __restrict__ out)
{
  const int tid  = threadIdx.x;
  const int bid  = blockIdx.x;
  const int lane = tid & 63;
  const int wave = tid >> 6;
  const int q = lane >> 4, cl = lane & 15;

  __shared__ float red[4][PP];
  __shared__ float alpha_s[PP];

  int ph = 0;

  // ---- load register-resident B fragments of [Wh;Whh] (whole w2 lives in VGPRs
  //      of the 640 persistent waves: 16 rows x 512 k-half per wave = 64 VGPR/lane)
  const int job = bid * 4 + wave;          // 0..639
  const int nt  = job >> 1;                // n-tile 0..319
  const int kh  = job & 1;                 // k-half
  const _Float16* Bb = w2 + (size_t)(nt * 16 + cl) * KK + kh * 512 + q * 8;
  f16x8 breg[16];
#pragma unroll
  for (int ks = 0; ks < 16; ks++)
    breg[ks] = *(const f16x8*)(Bb + ks * 32);

  // ---- zero-init h16 via coherence-point stores (visible to all sc-readers)
  if (bid < BB) {
    unsigned* p = (unsigned*)(h16 + (size_t)bid * HH);
    st_u32_sc(p + tid, 0u);
    st_u32_sc(p + 256 + tid, 0u);
  }
  // LSTM cell state lives in registers of the owning R23 thread
  float c_reg = 0.f;

  grid_barrier(flags, ++ph);

  for (int t = 0; t < TT; ++t) {
    // ---------- R1: a5 = h16 @ [Wh;Whh]^T, B from registers, A via sc-loads ----------
    {
      const _Float16* A0 = h16 + (size_t)cl * KK + kh * 512 + q * 8;   // b rows 0..15
      const _Float16* A1 = A0 + (size_t)16 * KK;                        // b rows 16..31
      f32x4 acc0 = {0.f, 0.f, 0.f, 0.f}, acc1 = {0.f, 0.f, 0.f, 0.f};
#pragma unroll
      for (int g = 0; g < 4; g++) {
        f16x8 a0[4], a1[4];
        load_a8_sc(A0 + (g * 4 + 0) * 32, A0 + (g * 4 + 1) * 32,
                   A0 + (g * 4 + 2) * 32, A0 + (g * 4 + 3) * 32,
                   A1 + (g * 4 + 0) * 32, A1 + (g * 4 + 1) * 32,
                   A1 + (g * 4 + 2) * 32, A1 + (g * 4 + 3) * 32,
                   a0[0], a0[1], a0[2], a0[3], a1[0], a1[1], a1[2], a1[3]);
#pragma unroll
        for (int j = 0; j < 4; j++) {
          acc0 = __builtin_amdgcn_mfma_f32_16x16x32_f16(a0[j], breg[g * 4 + j], acc0, 0, 0, 0);
          acc1 = __builtin_amdgcn_mfma_f32_16x16x32_f16(a1[j], breg[g * 4 + j], acc1, 0, 0, 0);
        }
      }
      float* a5w = kh ? a5b : a5a;
#pragma unroll
      for (int r = 0; r < 4; r++) {
        st_f32_sc(a5w + (size_t)(q * 4 + r) * NN + nt * 16 + cl,      acc0[r]);
        st_f32_sc(a5w + (size_t)(16 + q * 4 + r) * NN + nt * 16 + cl, acc1[r]);
      }
    }
    grid_barrier(flags, ++ph);

    // ---------- R23: attention softmax + gates + LSTM pointwise ----------
    if (bid < 128) {
      const int b  = bid & 31;
      const int us = bid >> 5;
      const int u  = us * 256 + tid;
      const size_t rbase = ((size_t)b * TT + t) * PP;

      // issue read-only xw loads first (normal cached); the sc-batch's waitcnt
      // folds their latency into one window
      f16x4 xv[PP];
#pragma unroll
      for (int p = 0; p < PP; p++)
        xv[p] = ((const f16x4*)(xw + (rbase + p) * NN))[tid];
      _Float16 xg[4][PP];
#pragma unroll
      for (int gi = 0; gi < 4; gi++)
#pragma unroll
        for (int p = 0; p < PP; p++)
          xg[gi][p] = xw[(rbase + p) * NN + HH + gi * HH + u];

      const float* pa = a5a + (size_t)b * NN + 4 * tid;
      const float* pb = a5b + (size_t)b * NN + 4 * tid;
      const float* g0a = a5a + (size_t)b * NN + HH + u;
      const float* g0b = a5b + (size_t)b * NN + HH + u;
      f32x4 va, vb;
      float ga0, ga1, ga2, ga3, gb0, gb1, gb2, gb3;
      ld_att_gates_sc(pa, pb,
                      g0a, g0a + HH, g0a + 2 * HH, g0a + 3 * HH,
                      g0b, g0b + HH, g0b + 2 * HH, g0b + 3 * HH,
                      va, vb, ga0, ga1, ga2, ga3, gb0, gb1, gb2, gb3);

      // scores
      f32x4 vv = ((const f32x4*)v)[tid];
      f32x4 aa = va + vb + ((const f32x4*)b_att)[tid];
      float part[PP];
#pragma unroll
      for (int p = 0; p < PP; p++) {
        f32x4 xf = __builtin_convertvector(xv[p], f32x4);
        float s = 0.f;
#pragma unroll
        for (int j = 0; j < 4; j++)
          s += vv[j] * fast_tanh(aa[j] + xf[j]);
        part[p] = s;
      }
#pragma unroll
      for (int p = 0; p < PP; p++) {
        float s = part[p];
        s += __shfl_down(s, 32); s += __shfl_down(s, 16); s += __shfl_down(s, 8);
        s += __shfl_down(s, 4);  s += __shfl_down(s, 2);  s += __shfl_down(s, 1);
        if (lane == 0) red[wave][p] = s;
      }
      __syncthreads();
      if (tid == 0) {
        float sc[PP]; float mx = -1e30f;
#pragma unroll
        for (int p = 0; p < PP; p++) {
          sc[p] = red[0][p] + red[1][p] + red[2][p] + red[3][p];
          mx = fmaxf(mx, sc[p]);
        }
        float den = 0.f;
#pragma unroll
        for (int p = 0; p < PP; p++) { sc[p] = __expf(sc[p] - mx); den += sc[p]; }
        float inv = 1.0f / den;
#pragma unroll
        for (int p = 0; p < PP; p++) alpha_s[p] = sc[p] * inv;
      }
      __syncthreads();
      float al[PP];
#pragma unroll
      for (int p = 0; p < PP; p++) al[p] = alpha_s[p];

      float gsum[4] = {ga0 + gb0, ga1 + gb1, ga2 + gb2, ga3 + gb3};
      float gv[4];
#pragma unroll
      for (int gi = 0; gi < 4; gi++) {
        float s = gsum[gi] + bih[gi * HH + u] + bhh[gi * HH + u];
#pragma unroll
        for (int p = 0; p < PP; p++)
          s += al[p] * (float)xg[gi][p];
        gv[gi] = s;
      }
      float ig = fast_sigm(gv[0]);
      float fg = fast_sigm(gv[1]);
      float gg = fast_tanh(gv[2]);
      float og = fast_sigm(gv[3]);
      float cn = fg * c_reg + ig * gg;
      float hn = og * fast_tanh(cn);
      c_reg = cn;
      _Float16 h16v = (_Float16)hn;
      st_u16_sc((unsigned short*)(h16 + (size_t)b * HH + u),
                (unsigned)__builtin_bit_cast(unsigned short, h16v));
      if (t == TT - 1)
        st_f32_sc(h + (size_t)b * HH + u, hn);
    }
    grid_barrier(flags, ++ph);
  }

  // ---------- final FC: out = h @ Wfc^T + bfc ----------
  if (bid < BB) {
    const int b = bid;
    f32x4 hv = ld_f32x4_sc(h + (size_t)b * HH + 4 * tid);
    float pc[CC];
#pragma unroll
    for (int cc2 = 0; cc2 < CC; cc2++) {
      f32x4 wv = ((const f32x4*)(Wfc + (size_t)cc2 * HH))[tid];
      pc[cc2] = hv[0]*wv[0] + hv[1]*wv[1] + hv[2]*wv[2] + hv[3]*wv[3];
    }
#pragma unroll
    for (int cc2 = 0; cc2 < CC; cc2++) {
      float s = pc[cc2];
      s += __shfl_down(s, 32); s += __shfl_down(s, 16); s += __shfl_down(s, 8);
      s += __shfl_down(s, 4);  s += __shfl_down(s, 2);  s += __shfl_down(s, 1);
      if (lane == 0) red[wave][cc2] = s;
    }
    __syncthreads();
    if (tid < CC)
      out[b * CC + tid] = red[0][tid] + red[1][tid] + red[2][tid] + red[3][tid] + bfc[tid];
  }
}

// ---------------- host entry ----------------
extern "C" void kernel_launch(void* const* d_in, const int* in_sizes, int n_in,
                              void* d_out, int out_size, void* d_ws, size_t ws_size,
                              hipStream_t stream)
{
  (void)in_sizes; (void)n_in; (void)out_size; (void)ws_size;
  const float* x     = (const float*)d_in[0];
  const float* Wx    = (const float*)d_in[1];
  const float* Wh    = (const float*)d_in[2];
  const float* b_att = (const float*)d_in[3];
  const float* v     = (const float*)d_in[4];
  const float* Wih   = (const float*)d_in[5];
  const float* Whh   = (const float*)d_in[6];
  const float* bih   = (const float*)d_in[7];
  const float* bhh   = (const float*)d_in[8];
  const float* Wfc   = (const float*)d_in[9];
  const float* bfc   = (const float*)d_in[10];
  float* out = (float*)d_out;

  char* ws = (char*)d_ws;
  size_t off = 0;
  auto alloc = [&](size_t bytes) {
    size_t o = off;
    off += (bytes + 255) & ~(size_t)255;
    return o;
  };
  int*      flags = (int*)      (ws + alloc(16384));                 // barrier flags + gen
  _Float16* xh    = (_Float16*) (ws + alloc((size_t)MM * KK * 2));   //  42 MB
  _Float16* w5    = (_Float16*) (ws + alloc((size_t)NN * KK * 2));   //  10.5 MB
  _Float16* w2    = (_Float16*) (ws + alloc((size_t)NN * KK * 2));   //  10.5 MB
  _Float16* xw    = (_Float16*) (ws + alloc((size_t)MM * NN * 2));   // 210 MB
  float*    a5a   = (float*)    (ws + alloc((size_t)BB * NN * 4));
  float*    a5b   = (float*)    (ws + alloc((size_t)BB * NN * 4));
  float*    h     = (float*)    (ws + alloc((size_t)BB * HH * 4));
  _Float16* h16   = (_Float16*) (ws + alloc((size_t)BB * HH * 2));

  hipMemsetAsync(flags, 0, 16384, stream);
  convert_kernel<<<2048, 256, 0, stream>>>(x, Wx, Wih, Wh, Whh, xh, w5, w2);
  gemm_kernel<<<6400, 256, 0, stream>>>(xh, w5, xw);
  recur_kernel<<<NBLK, 256, 0, stream>>>(xw, w2, a5a, a5b, h, h16, flags,
                                         b_att, v, bih, bhh, Wfc, bfc, out);
}

// Round 4
// 1251.270 us; speedup vs baseline: 4.2985x; 1.1167x over previous
//
#include <hip/hip_runtime.h>

// ---------------- problem constants ----------------
#define BB 32
#define TT 64
#define PP 10
#define HH 1024
#define CC 8
#define MM 20480      // BB*TT*PP rows of x_flat
#define NN 5120       // 5*HH  ([Wx;Wih] rows, and [Wh;Whh] rows)
#define KK 1024       // I == H
#define RBLK 128      // R23 blocks (32 b x 4 unit-slices)
#define GBLK 80       // R1 (recurrent GEMM) blocks, 4 waves each = 320 waves
#define GRID (RBLK + GBLK)   // 208 <= 256 CUs -> co-resident

typedef __attribute__((ext_vector_type(4))) float    f32x4;
typedef __attribute__((ext_vector_type(4))) _Float16 f16x4;
typedef __attribute__((ext_vector_type(8))) _Float16 f16x8;

#define AS1C(p) ((const __attribute__((address_space(1))) void*)(p))
#define AS3(p)  ((__attribute__((address_space(3))) void*)(p))

__device__ __forceinline__ float fast_tanh(float x) {
  float ax = __builtin_fabsf(x);
  float e  = __expf(2.0f * ax);
  float r  = 1.0f - 2.0f / (e + 1.0f);   // -> 1 as e -> inf (no NaN)
  return __builtin_copysignf(r, x);
}
__device__ __forceinline__ float fast_sigm(float x) {
  return 1.0f / (1.0f + __expf(-x));
}

// ---------- coherence-point (sc0 sc1) access helpers: bypass L1+L2 ----------
__device__ __forceinline__ int ld_flag(const int* p) {
  int r;
  asm volatile("global_load_dword %0, %1, off sc0 sc1\n\ts_waitcnt vmcnt(0)"
               : "=v"(r) : "v"(p) : "memory");
  return r;
}
__device__ __forceinline__ void st_flag(int* p, int v) {
  asm volatile("global_store_dword %0, %1, off sc0 sc1" :: "v"(p), "v"(v) : "memory");
}
__device__ __forceinline__ void st_f32_sc(float* p, float v) {
  asm volatile("global_store_dword %0, %1, off sc0 sc1" :: "v"(p), "v"(v) : "memory");
}
__device__ __forceinline__ void st_u32_sc(unsigned* p, unsigned v) {
  asm volatile("global_store_dword %0, %1, off sc0 sc1" :: "v"(p), "v"(v) : "memory");
}
__device__ __forceinline__ void st_u16_sc(unsigned short* p, unsigned v) {
  asm volatile("global_store_short %0, %1, off sc0 sc1" :: "v"(p), "v"(v) : "memory");
}
__device__ __forceinline__ f32x4 ld_f32x4_sc(const float* p) {
  f32x4 r;
  asm volatile("global_load_dwordx4 %0, %1, off sc0 sc1\n\ts_waitcnt vmcnt(0)"
               : "=v"(r) : "v"(p) : "memory");
  return r;
}
__device__ __forceinline__ void vm_drain() {
  asm volatile("s_waitcnt vmcnt(0)" ::: "memory");
}

// 8 x 16B loads, NO wait (manual vmcnt pipelining)
__device__ __forceinline__ void load8_nw(
    const _Float16* p0, const _Float16* p1, const _Float16* p2, const _Float16* p3,
    const _Float16* p4, const _Float16* p5, const _Float16* p6, const _Float16* p7,
    f16x8& d0, f16x8& d1, f16x8& d2, f16x8& d3,
    f16x8& d4, f16x8& d5, f16x8& d6, f16x8& d7)
{
  asm volatile(
    "global_load_dwordx4 %0, %8, off sc0 sc1\n\t"
    "global_load_dwordx4 %1, %9, off sc0 sc1\n\t"
    "global_load_dwordx4 %2, %10, off sc0 sc1\n\t"
    "global_load_dwordx4 %3, %11, off sc0 sc1\n\t"
    "global_load_dwordx4 %4, %12, off sc0 sc1\n\t"
    "global_load_dwordx4 %5, %13, off sc0 sc1\n\t"
    "global_load_dwordx4 %6, %14, off sc0 sc1\n\t"
    "global_load_dwordx4 %7, %15, off sc0 sc1"
    : "=v"(d0), "=v"(d1), "=v"(d2), "=v"(d3), "=v"(d4), "=v"(d5), "=v"(d6), "=v"(d7)
    : "v"(p0), "v"(p1), "v"(p2), "v"(p3), "v"(p4), "v"(p5), "v"(p6), "v"(p7)
    : "memory");
}
// wait until <=8 outstanding vmem ops; ties the 8 values so MFMA can't hoist above
__device__ __forceinline__ void wait_vm8_tie(
    f16x8& d0, f16x8& d1, f16x8& d2, f16x8& d3,
    f16x8& d4, f16x8& d5, f16x8& d6, f16x8& d7)
{
  asm volatile("s_waitcnt vmcnt(8)"
    : "+v"(d0), "+v"(d1), "+v"(d2), "+v"(d3), "+v"(d4), "+v"(d5), "+v"(d6), "+v"(d7));
}
__device__ __forceinline__ void wait_vm0_tie(
    f16x8& d0, f16x8& d1, f16x8& d2, f16x8& d3,
    f16x8& d4, f16x8& d5, f16x8& d6, f16x8& d7)
{
  asm volatile("s_waitcnt vmcnt(0)"
    : "+v"(d0), "+v"(d1), "+v"(d2), "+v"(d3), "+v"(d4), "+v"(d5), "+v"(d6), "+v"(d7));
}
// att (2 x dwordx4) + gates (8 x dword) in one latency window
__device__ __forceinline__ void ld_att_gates_sc(
    const float* pa, const float* pb,
    const float* q0, const float* q1, const float* q2, const float* q3,
    const float* q4, const float* q5, const float* q6, const float* q7,
    f32x4& ra, f32x4& rb,
    float& r0, float& r1, float& r2, float& r3,
    float& r4, float& r5, float& r6, float& r7)
{
  asm volatile(
    "global_load_dwordx4 %0, %10, off sc0 sc1\n\t"
    "global_load_dwordx4 %1, %11, off sc0 sc1\n\t"
    "global_load_dword %2, %12, off sc0 sc1\n\t"
    "global_load_dword %3, %13, off sc0 sc1\n\t"
    "global_load_dword %4, %14, off sc0 sc1\n\t"
    "global_load_dword %5, %15, off sc0 sc1\n\t"
    "global_load_dword %6, %16, off sc0 sc1\n\t"
    "global_load_dword %7, %17, off sc0 sc1\n\t"
    "global_load_dword %8, %18, off sc0 sc1\n\t"
    "global_load_dword %9, %19, off sc0 sc1\n\t"
    "s_waitcnt vmcnt(0)"
    : "=v"(ra), "=v"(rb), "=v"(r0), "=v"(r1), "=v"(r2), "=v"(r3),
      "=v"(r4), "=v"(r5), "=v"(r6), "=v"(r7)
    : "v"(pa), "v"(pb), "v"(q0), "v"(q1), "v"(q2), "v"(q3),
      "v"(q4), "v"(q5), "v"(q6), "v"(q7)
    : "memory");
}

// ---------------- fp32 -> fp16 conversion / weight concat ----------------
__global__ void convert_kernel(const float* __restrict__ x,
                               const float* __restrict__ Wx,
                               const float* __restrict__ Wih,
                               const float* __restrict__ Wh,
                               const float* __restrict__ Whh,
                               _Float16* __restrict__ xh,
                               _Float16* __restrict__ w5,
                               _Float16* __restrict__ w2)
{
  const long gid    = (long)blockIdx.x * blockDim.x + threadIdx.x;
  const long stride = (long)gridDim.x * blockDim.x;
  auto cvt = [&](const float* src, _Float16* dst, long n4) {
    const f32x4* s4 = (const f32x4*)src;
    f16x4* d4 = (f16x4*)dst;
    for (long i = gid; i < n4; i += stride)
      d4[i] = __builtin_convertvector(s4[i], f16x4);
  };
  cvt(x,   xh,                 (long)MM * KK / 4);
  cvt(Wx,  w5,                 (long)HH * KK / 4);
  cvt(Wih, w5 + (long)HH * KK, (long)4 * HH * KK / 4);
  cvt(Wh,  w2,                 (long)HH * KK / 4);
  cvt(Whh, w2 + (long)HH * KK, (long)4 * HH * KK / 4);
}

// ---------------- big precompute GEMM: xW5 = x_f16 @ [Wx;Wih]^T ----------------
__global__ __launch_bounds__(256) void gemm_kernel(const _Float16* __restrict__ A,
                                                   const _Float16* __restrict__ Bw,
                                                   _Float16* __restrict__ Cw)
{
  __shared__ __align__(16) _Float16 sA[128 * 64];
  __shared__ __align__(16) _Float16 sB[128 * 64];
  const int t    = threadIdx.x;
  const int lane = t & 63;
  const int wave = t >> 6;
  const int wm = wave >> 1, wn = wave & 1;
  const int q = lane >> 4, cl = lane & 15;

  const int gid   = blockIdx.x;
  const int panel = gid / 640;
  const int w     = gid % 640;
  const int bm = panel * 16 + (w & 15);  // 0..159
  const int bn = w >> 4;                 // 0..39

  const _Float16* Ag = A  + (size_t)bm * 128 * KK;
  const _Float16* Bg = Bw + (size_t)bn * 128 * KK;

  f32x4 acc[4][4];
#pragma unroll
  for (int mi = 0; mi < 4; mi++)
#pragma unroll
    for (int ni = 0; ni < 4; ni++)
      acc[mi][ni] = (f32x4){0.f, 0.f, 0.f, 0.f};

  for (int k0 = 0; k0 < KK; k0 += 64) {
#pragma unroll
    for (int i = 0; i < 4; i++) {
      int c = t + 256 * i;
      int row = c >> 3, col8 = c & 7;
      __builtin_amdgcn_global_load_lds(AS1C(Ag + (size_t)row * KK + k0 + col8 * 8),
                                       AS3(sA + c * 8), 16, 0, 0);
      __builtin_amdgcn_global_load_lds(AS1C(Bg + (size_t)row * KK + k0 + col8 * 8),
                                       AS3(sB + c * 8), 16, 0, 0);
    }
    __syncthreads();
#pragma unroll
    for (int ks = 0; ks < 2; ks++) {
      f16x8 af[4], bf[4];
#pragma unroll
      for (int mi = 0; mi < 4; mi++)
        af[mi] = *(const f16x8*)(sA + (wm * 64 + mi * 16 + cl) * 64 + ks * 32 + q * 8);
#pragma unroll
      for (int ni = 0; ni < 4; ni++)
        bf[ni] = *(const f16x8*)(sB + (wn * 64 + ni * 16 + cl) * 64 + ks * 32 + q * 8);
#pragma unroll
      for (int mi = 0; mi < 4; mi++)
#pragma unroll
        for (int ni = 0; ni < 4; ni++)
          acc[mi][ni] = __builtin_amdgcn_mfma_f32_16x16x32_f16(af[mi], bf[ni], acc[mi][ni], 0, 0, 0);
    }
    __syncthreads();
  }

#pragma unroll
  for (int mi = 0; mi < 4; mi++)
#pragma unroll
    for (int ni = 0; ni < 4; ni++)
#pragma unroll
      for (int r = 0; r < 4; r++) {
        int row = bm * 128 + wm * 64 + mi * 16 + q * 4 + r;
        int col = bn * 128 + wn * 64 + ni * 16 + cl;
        Cw[(size_t)row * NN + col] = (_Float16)acc[mi][ni][r];
      }
}

// ---------------- persistent recurrence kernel (producer-consumer flags) -------
// flagY[j] (j<128, at flags[j*16])       : R23 block j completed Y-phase; value = t+2
//                                          (init post = 1 after h16 zeros flushed)
// flagX[i] (i<80, at flags[(128+i)*16])  : R1 block i completed X-phase; value = t+1
// WAR safety: a flag post data-depends on all reads of that phase (vm_drain before
// post), so a posted flag also certifies the poster is done READING the buffer the
// other side will overwrite next.
__global__ __launch_bounds__(256, 1) void recur_kernel(
    const _Float16* __restrict__ xw,   // [MM][NN] fp16: cols 0..1023 att, 1024.. gates
    const _Float16* __restrict__ w2,   // [NN][KK] fp16: [Wh;Whh]
    float* __restrict__ a5a,           // [BB][NN] partial (k-half 0)
    float* __restrict__ a5b,           // [BB][NN] partial (k-half 1)
    float* __restrict__ h,             // [BB][HH] fp32 (final step only)
    _Float16* __restrict__ h16,        // [BB][HH] fp16 (MFMA A operand)
    int* __restrict__ flags,
    const float* __restrict__ b_att,
    const float* __restrict__ v,
    const float* __restrict__ bih,
    const float* __restrict__ bhh,
    const float* __restrict__ Wfc,
    const float* __restrict__ bfc,
    float* __restrict__ out)
{
  const int tid  = threadIdx.x;
  const int bid  = blockIdx.x;
  const int lane = tid & 63;
  const int wave = tid >> 6;
  const int q = lane >> 4, cl = lane & 15;

  __shared__ float red[4][PP];
  __shared__ float alpha_s[PP];

  if (bid >= RBLK) {
    // ================= R1 role: a5 = h16 @ [Wh;Whh]^T =================
    const int job  = (bid - RBLK) * 4 + wave;  // 0..319
    const int ngrp = job >> 1;                 // 0..159 (pair of n-tiles)
    const int kh   = job & 1;                  // k-half
    const int nt0  = ngrp * 2, nt1 = nt0 + 1;

    // register-resident B: 2 tiles x 16 rows x 512 k = 128 VGPR/lane
    f16x8 breg[2][16];
#pragma unroll
    for (int j = 0; j < 2; j++)
#pragma unroll
      for (int ks = 0; ks < 16; ks++)
        breg[j][ks] = *(const f16x8*)(w2 + (size_t)((nt0 + j) * 16 + cl) * KK
                                      + kh * 512 + ks * 32 + q * 8);

    float* a5w = kh ? a5b : a5a;
    const _Float16* A0 = h16 + (size_t)cl * KK + kh * 512 + q * 8;   // b rows 0..15
    const _Float16* A1 = A0 + (size_t)16 * KK;                        // b rows 16..31

    for (int t = 0; t < TT; ++t) {
      // wait all R23 blocks posted Y(t-1) (init: >=1 means h16 zeros visible)
      if (tid < RBLK)
        while (ld_flag(flags + tid * 16) < t + 1) {}
      __syncthreads();

      f32x4 acc00 = {0,0,0,0}, acc10 = {0,0,0,0}, acc01 = {0,0,0,0}, acc11 = {0,0,0,0};
      f16x8 w0[8], w1[8], w2r[8], w3[8];
      load8_nw(A0 + 0*32, A0 + 1*32, A0 + 2*32, A0 + 3*32,
               A0 + 4*32, A0 + 5*32, A0 + 6*32, A0 + 7*32,
               w0[0], w0[1], w0[2], w0[3], w0[4], w0[5], w0[6], w0[7]);
      load8_nw(A0 + 8*32, A0 + 9*32, A0 + 10*32, A0 + 11*32,
               A0 + 12*32, A0 + 13*32, A0 + 14*32, A0 + 15*32,
               w1[0], w1[1], w1[2], w1[3], w1[4], w1[5], w1[6], w1[7]);
      wait_vm8_tie(w0[0], w0[1], w0[2], w0[3], w0[4], w0[5], w0[6], w0[7]);
#pragma unroll
      for (int ks = 0; ks < 8; ks++) {
        acc00 = __builtin_amdgcn_mfma_f32_16x16x32_f16(w0[ks], breg[0][ks], acc00, 0, 0, 0);
        acc10 = __builtin_amdgcn_mfma_f32_16x16x32_f16(w0[ks], breg[1][ks], acc10, 0, 0, 0);
      }
      load8_nw(A1 + 0*32, A1 + 1*32, A1 + 2*32, A1 + 3*32,
               A1 + 4*32, A1 + 5*32, A1 + 6*32, A1 + 7*32,
               w2r[0], w2r[1], w2r[2], w2r[3], w2r[4], w2r[5], w2r[6], w2r[7]);
      wait_vm8_tie(w1[0], w1[1], w1[2], w1[3], w1[4], w1[5], w1[6], w1[7]);
#pragma unroll
      for (int ks = 0; ks < 8; ks++) {
        acc00 = __builtin_amdgcn_mfma_f32_16x16x32_f16(w1[ks], breg[0][8 + ks], acc00, 0, 0, 0);
        acc10 = __builtin_amdgcn_mfma_f32_16x16x32_f16(w1[ks], breg[1][8 + ks], acc10, 0, 0, 0);
      }
      load8_nw(A1 + 8*32, A1 + 9*32, A1 + 10*32, A1 + 11*32,
               A1 + 12*32, A1 + 13*32, A1 + 14*32, A1 + 15*32,
               w3[0], w3[1], w3[2], w3[3], w3[4], w3[5], w3[6], w3[7]);
      wait_vm8_tie(w2r[0], w2r[1], w2r[2], w2r[3], w2r[4], w2r[5], w2r[6], w2r[7]);
#pragma unroll
      for (int ks = 0; ks < 8; ks++) {
        acc01 = __builtin_amdgcn_mfma_f32_16x16x32_f16(w2r[ks], breg[0][ks], acc01, 0, 0, 0);
        acc11 = __builtin_amdgcn_mfma_f32_16x16x32_f16(w2r[ks], breg[1][ks], acc11, 0, 0, 0);
      }
      wait_vm0_tie(w3[0], w3[1], w3[2], w3[3], w3[4], w3[5], w3[6], w3[7]);
#pragma unroll
      for (int ks = 0; ks < 8; ks++) {
        acc01 = __builtin_amdgcn_mfma_f32_16x16x32_f16(w3[ks], breg[0][8 + ks], acc01, 0, 0, 0);
        acc11 = __builtin_amdgcn_mfma_f32_16x16x32_f16(w3[ks], breg[1][8 + ks], acc11, 0, 0, 0);
      }
#pragma unroll
      for (int r = 0; r < 4; r++) {
        st_f32_sc(a5w + (size_t)(q * 4 + r) * NN + nt0 * 16 + cl,      acc00[r]);
        st_f32_sc(a5w + (size_t)(q * 4 + r) * NN + nt1 * 16 + cl,      acc10[r]);
        st_f32_sc(a5w + (size_t)(16 + q * 4 + r) * NN + nt0 * 16 + cl, acc01[r]);
        st_f32_sc(a5w + (size_t)(16 + q * 4 + r) * NN + nt1 * 16 + cl, acc11[r]);
      }
      vm_drain();
      __syncthreads();
      if (tid == 0) st_flag(flags + bid * 16, t + 1);   // flagX slot (RBLK+i)*16 == bid*16
      __syncthreads();
    }
    return;
  }

  // ================= R23 role: attention + softmax + gates + LSTM =================
  const int b  = bid & 31;
  const int us = bid >> 5;
  const int u  = us * 256 + tid;

  // init: zero h16 (blocks 0..31), flush, post flagY = 1
  if (bid < BB) {
    unsigned* p = (unsigned*)(h16 + (size_t)bid * HH);
    st_u32_sc(p + tid, 0u);
    st_u32_sc(p + 256 + tid, 0u);
  }
  vm_drain();
  __syncthreads();
  if (tid == 0) st_flag(flags + bid * 16, 1);

  // loop-invariant hoists
  f32x4 vv   = ((const f32x4*)v)[tid];
  f32x4 batt = ((const f32x4*)b_att)[tid];
  float bsum[4];
#pragma unroll
  for (int gi = 0; gi < 4; gi++)
    bsum[gi] = bih[gi * HH + u] + bhh[gi * HH + u];
  float c_reg = 0.f;

  for (int t = 0; t < TT; ++t) {
    const size_t rbase = ((size_t)b * TT + t) * PP;

    // prefetch xw for this step (normal cached loads, issued before flagX wait)
    f16x4 xv[PP];
#pragma unroll
    for (int p = 0; p < PP; p++)
      xv[p] = ((const f16x4*)(xw + (rbase + p) * NN))[tid];
    _Float16 xg[4][PP];
#pragma unroll
    for (int gi = 0; gi < 4; gi++)
#pragma unroll
      for (int p = 0; p < PP; p++)
        xg[gi][p] = xw[(rbase + p) * NN + HH + gi * HH + u];

    // wait all R1 blocks posted X(t)
    if (tid < GBLK)
      while (ld_flag(flags + (RBLK + tid) * 16) < t + 1) {}
    __syncthreads();

    const float* pa  = a5a + (size_t)b * NN + 4 * tid;
    const float* pb  = a5b + (size_t)b * NN + 4 * tid;
    const float* g0a = a5a + (size_t)b * NN + HH + u;
    const float* g0b = a5b + (size_t)b * NN + HH + u;
    f32x4 va, vb;
    float ga0, ga1, ga2, ga3, gb0, gb1, gb2, gb3;
    ld_att_gates_sc(pa, pb,
                    g0a, g0a + HH, g0a + 2 * HH, g0a + 3 * HH,
                    g0b, g0b + HH, g0b + 2 * HH, g0b + 3 * HH,
                    va, vb, ga0, ga1, ga2, ga3, gb0, gb1, gb2, gb3);

    // scores
    f32x4 aa = va + vb + batt;
    float part[PP];
#pragma unroll
    for (int p = 0; p < PP; p++) {
      f32x4 xf = __builtin_convertvector(xv[p], f32x4);
      float s = 0.f;
#pragma unroll
      for (int j = 0; j < 4; j++)
        s += vv[j] * fast_tanh(aa[j] + xf[j]);
      part[p] = s;
    }
#pragma unroll
    for (int p = 0; p < PP; p++) {
      float s = part[p];
      s += __shfl_down(s, 32); s += __shfl_down(s, 16); s += __shfl_down(s, 8);
      s += __shfl_down(s, 4);  s += __shfl_down(s, 2);  s += __shfl_down(s, 1);
      if (lane == 0) red[wave][p] = s;
    }
    __syncthreads();
    if (tid == 0) {
      float sc[PP]; float mx = -1e30f;
#pragma unroll
      for (int p = 0; p < PP; p++) {
        sc[p] = red[0][p] + red[1][p] + red[2][p] + red[3][p];
        mx = fmaxf(mx, sc[p]);
      }
      float den = 0.f;
#pragma unroll
      for (int p = 0; p < PP; p++) { sc[p] = __expf(sc[p] - mx); den += sc[p]; }
      float inv = 1.0f / den;
#pragma unroll
      for (int p = 0; p < PP; p++) alpha_s[p] = sc[p] * inv;
    }
    __syncthreads();
    float al[PP];
#pragma unroll
    for (int p = 0; p < PP; p++) al[p] = alpha_s[p];

    float gsum[4] = {ga0 + gb0, ga1 + gb1, ga2 + gb2, ga3 + gb3};
    float gv[4];
#pragma unroll
    for (int gi = 0; gi < 4; gi++) {
      float s = gsum[gi] + bsum[gi];
#pragma unroll
      for (int p = 0; p < PP; p++)
        s += al[p] * (float)xg[gi][p];
      gv[gi] = s;
    }
    float ig = fast_sigm(gv[0]);
    float fg = fast_sigm(gv[1]);
    float gg = fast_tanh(gv[2]);
    float og = fast_sigm(gv[3]);
    float cn = fg * c_reg + ig * gg;
    float hn = og * fast_tanh(cn);
    c_reg = cn;
    _Float16 h16v = (_Float16)hn;
    st_u16_sc((unsigned short*)(h16 + (size_t)b * HH + u),
              (unsigned)__builtin_bit_cast(unsigned short, h16v));
    if (t == TT - 1)
      st_f32_sc(h + (size_t)b * HH + u, hn);

    // flush + post flagY = t+2
    vm_drain();
    __syncthreads();
    if (tid == 0) st_flag(flags + bid * 16, t + 2);
    __syncthreads();
  }

  // ---------- final FC (blocks 0..31): out = h @ Wfc^T + bfc ----------
  if (bid < BB) {
    // wait for the 3 peer unit-slice blocks to finish step TT-1
    if (tid >= 1 && tid <= 3)
      while (ld_flag(flags + (bid + 32 * tid) * 16) < TT + 1) {}
    __syncthreads();
    f32x4 hv = ld_f32x4_sc(h + (size_t)bid * HH + 4 * tid);
    float pc[CC];
#pragma unroll
    for (int cc2 = 0; cc2 < CC; cc2++) {
      f32x4 wv = ((const f32x4*)(Wfc + (size_t)cc2 * HH))[tid];
      pc[cc2] = hv[0]*wv[0] + hv[1]*wv[1] + hv[2]*wv[2] + hv[3]*wv[3];
    }
#pragma unroll
    for (int cc2 = 0; cc2 < CC; cc2++) {
      float s = pc[cc2];
      s += __shfl_down(s, 32); s += __shfl_down(s, 16); s += __shfl_down(s, 8);
      s += __shfl_down(s, 4);  s += __shfl_down(s, 2);  s += __shfl_down(s, 1);
      if (lane == 0) red[wave][cc2] = s;
    }
    __syncthreads();
    if (tid < CC)
      out[bid * CC + tid] = red[0][tid] + red[1][tid] + red[2][tid] + red[3][tid] + bfc[tid];
  }
}

// ---------------- host entry ----------------
extern "C" void kernel_launch(void* const* d_in, const int* in_sizes, int n_in,
                              void* d_out, int out_size, void* d_ws, size_t ws_size,
                              hipStream_t stream)
{
  (void)in_sizes; (void)n_in; (void)out_size; (void)ws_size;
  const float* x     = (const float*)d_in[0];
  const float* Wx    = (const float*)d_in[1];
  const float* Wh    = (const float*)d_in[2];
  const float* b_att = (const float*)d_in[3];
  const float* v     = (const float*)d_in[4];
  const float* Wih   = (const float*)d_in[5];
  const float* Whh   = (const float*)d_in[6];
  const float* bih   = (const float*)d_in[7];
  const float* bhh   = (const float*)d_in[8];
  const float* Wfc   = (const float*)d_in[9];
  const float* bfc   = (const float*)d_in[10];
  float* out = (float*)d_out;

  char* ws = (char*)d_ws;
  size_t off = 0;
  auto alloc = [&](size_t bytes) {
    size_t o = off;
    off += (bytes + 255) & ~(size_t)255;
    return o;
  };
  int*      flags = (int*)      (ws + alloc(65536));                 // flagY[128], flagX[80]
  _Float16* xh    = (_Float16*) (ws + alloc((size_t)MM * KK * 2));   //  42 MB
  _Float16* w5    = (_Float16*) (ws + alloc((size_t)NN * KK * 2));   //  10.5 MB
  _Float16* w2    = (_Float16*) (ws + alloc((size_t)NN * KK * 2));   //  10.5 MB
  _Float16* xw    = (_Float16*) (ws + alloc((size_t)MM * NN * 2));   // 210 MB
  float*    a5a   = (float*)    (ws + alloc((size_t)BB * NN * 4));
  float*    a5b   = (float*)    (ws + alloc((size_t)BB * NN * 4));
  float*    h     = (float*)    (ws + alloc((size_t)BB * HH * 4));
  _Float16* h16   = (_Float16*) (ws + alloc((size_t)BB * HH * 2));

  hipMemsetAsync(flags, 0, 65536, stream);
  convert_kernel<<<2048, 256, 0, stream>>>(x, Wx, Wih, Wh, Whh, xh, w5, w2);
  gemm_kernel<<<6400, 256, 0, stream>>>(xh, w5, xw);
  recur_kernel<<<GRID, 256, 0, stream>>>(xw, w2, a5a, a5b, h, h16, flags,
                                         b_att, v, bih, bhh, Wfc, bfc, out);
}